// Round 6
// baseline (241.156 us; speedup 1.0000x reference)
//
#include <hip/hip_runtime.h>
#include <hip/hip_bf16.h>

typedef __bf16 bf16x8 __attribute__((ext_vector_type(8)));
typedef float  f32x4  __attribute__((ext_vector_type(4)));

static constexpr int S  = 64;    // DIM_S
static constexpr int C  = 8;     // DIM_C (experts)
static constexpr int HD = 256;   // hidden width

__device__ __forceinline__ unsigned short f2bf(float f) {
  __hip_bfloat16 b = __float2bfloat16(f);
  unsigned short u;
  __builtin_memcpy(&u, &b, 2);
  return u;
}

// LDS-tiled transposes, coalesced both sides.
// blocks 0..511:  W2 [C][256k][256n] -> W2T bf16 [C][256n][256k]
// blocks 512..639: W1 [C][64s][256h] -> W1T bf16 [C][256h][64s]
__global__ __launch_bounds__(256) void prep_weights(
    const float* __restrict__ W1, const float* __restrict__ W2,
    unsigned short* __restrict__ W1T, unsigned short* __restrict__ W2T)
{
  __shared__ float tile[32][33];
  const int tid = threadIdx.x, cl = tid & 31, r0 = tid >> 5;
  const int b = blockIdx.x;
  if (b < 512) {
    const int c = b >> 6, t = b & 63, kt = t >> 3, nt = t & 7;
    const float* src = W2 + c * 65536;
    #pragma unroll
    for (int i = 0; i < 4; ++i) {
      int r = r0 + 8 * i;
      tile[r][cl] = src[(kt * 32 + r) * 256 + nt * 32 + cl];
    }
    __syncthreads();
    unsigned short* dst = W2T + c * 65536;
    #pragma unroll
    for (int i = 0; i < 4; ++i) {
      int r = r0 + 8 * i;
      dst[(nt * 32 + r) * 256 + kt * 32 + cl] = f2bf(tile[cl][r]);
    }
  } else {
    const int bb = b - 512;
    const int c = bb >> 4, t = bb & 15, st2 = t >> 3, ht = t & 7;
    const float* src = W1 + c * 16384;
    #pragma unroll
    for (int i = 0; i < 4; ++i) {
      int r = r0 + 8 * i;
      tile[r][cl] = src[(st2 * 32 + r) * 256 + ht * 32 + cl];
    }
    __syncthreads();
    unsigned short* dst = W1T + c * 16384;
    #pragma unroll
    for (int i = 0; i < 4; ++i) {
      int r = r0 + 8 * i;
      dst[(ht * 32 + r) * 64 + st2 * 32 + cl] = f2bf(tile[cl][r]);
    }
  }
}

// One block: 256 batch rows x 1 expert. 4 waves, 64 rows/wave.
// c-major grid (c = blockIdx>>8): resident blocks share 1-2 experts -> W1T/W2T L1/L2-hot.
// NO __syncthreads anywhere: phase 1 transpose is wave-private in sT; phase 2
// streams W2T B-frags straight from global (no LDS, no DMA, no barriers).
// LDS = 36864 B only. Registers (~256 V+A) cap occupancy at 2 blocks/CU.
__global__ __launch_bounds__(256, 2) void moe_fused(
    const float* __restrict__ st,
    const unsigned short* __restrict__ W1T,
    const unsigned short* __restrict__ W2T,
    const float* __restrict__ b1,
    const float* __restrict__ b2,
    const float* __restrict__ W3,
    const float* __restrict__ b3,
    float* __restrict__ out)
{
  constexpr int LDT = 72;   // sT pitch: 64 hidden-local + 8 pad bf16 (144 B rows)

  // sT holds one 64-hidden quarter of h1^T, batch-major: [256 batch][72]
  __shared__ __align__(16) unsigned short sT[256 * LDT];     // 36864 B

  const int tid  = threadIdx.x;
  const int lane = tid & 63;
  const int wv   = tid >> 6;          // wave -> batch rows [wv*64, wv*64+64)
  const int l15  = lane & 15;
  const int q    = lane >> 4;
  const int c    = blockIdx.x >> 8;
  const int row0 = (blockIdx.x & 255) * 256;

  const unsigned short* W1c = W1T + c * HD * S;
  const unsigned short* W2c = W2T + c * HD * HD;

  // ---- st B-fragments (batch as N): lane holds st[row][s=q*8+j], fp32->bf16 ----
  bf16x8 aA[4][2];   // [nt][ks]
  #pragma unroll
  for (int nt = 0; nt < 4; ++nt)
    #pragma unroll
    for (int ks = 0; ks < 2; ++ks) {
      const int row = row0 + wv * 64 + nt * 16 + l15;
      const float4* p = reinterpret_cast<const float4*>(st + (size_t)row * S + ks * 32 + q * 8);
      float4 x = p[0], y = p[1];
      union { bf16x8 v; unsigned short u[8]; } a;
      a.u[0] = f2bf(x.x); a.u[1] = f2bf(x.y); a.u[2] = f2bf(x.z); a.u[3] = f2bf(x.w);
      a.u[4] = f2bf(y.x); a.u[5] = f2bf(y.y); a.u[6] = f2bf(y.z); a.u[7] = f2bf(y.w);
      aA[nt][ks] = a.v;
    }

  // ---- phase 1 TRANSPOSED: h1^T[hidden][batch] = W1^T @ st^T, 4 quarters ----
  // A = W1T rows (hidden as M), B = st rows (batch as N). C-layout then gives
  // each lane 4 CONSECUTIVE hidden values -> packed ds_write_b64 transpose.
  bf16x8 aF[4][4][2];  // [cc][rt][k2]: phase-2 A-frags (batch m=l15, k=hidden)
  #pragma unroll
  for (int cc = 0; cc < 4; ++cc) {
    f32x4 acc[4][4];   // [mt(hidden)][nt(batch)]
    #pragma unroll
    for (int mt = 0; mt < 4; ++mt)
      #pragma unroll
      for (int nt = 0; nt < 4; ++nt)
        acc[mt][nt] = (f32x4){0.f, 0.f, 0.f, 0.f};

    #pragma unroll
    for (int ks = 0; ks < 2; ++ks) {
      const int koff = ks * 32 + q * 8;
      bf16x8 aW[4];
      #pragma unroll
      for (int mt = 0; mt < 4; ++mt)
        aW[mt] = *reinterpret_cast<const bf16x8*>(
            W1c + (cc * 64 + mt * 16 + l15) * S + koff);
      #pragma unroll
      for (int mt = 0; mt < 4; ++mt)
        #pragma unroll
        for (int nt = 0; nt < 4; ++nt)
          acc[mt][nt] = __builtin_amdgcn_mfma_f32_16x16x32_bf16(
              aW[mt], aA[nt][ks], acc[mt][nt], 0, 0, 0);
    }

    // epilogue: +bias, relu, pack 4 consecutive hidden -> one b64 write.
    // sT rows [wv*64, wv*64+64) are wave-private: lgkmcnt drain, no barrier.
    #pragma unroll
    for (int mt = 0; mt < 4; ++mt) {
      const f32x4 bias = *reinterpret_cast<const f32x4*>(
          b1 + c * HD + cc * 64 + mt * 16 + q * 4);
      #pragma unroll
      for (int nt = 0; nt < 4; ++nt) {
        ushort4 pk;
        float v0 = acc[mt][nt][0] + bias[0]; v0 = v0 > 0.f ? v0 : 0.f;
        float v1 = acc[mt][nt][1] + bias[1]; v1 = v1 > 0.f ? v1 : 0.f;
        float v2 = acc[mt][nt][2] + bias[2]; v2 = v2 > 0.f ? v2 : 0.f;
        float v3 = acc[mt][nt][3] + bias[3]; v3 = v3 > 0.f ? v3 : 0.f;
        pk.x = f2bf(v0); pk.y = f2bf(v1); pk.z = f2bf(v2); pk.w = f2bf(v3);
        *reinterpret_cast<ushort4*>(
            sT + (wv * 64 + nt * 16 + l15) * LDT + mt * 16 + q * 4) = pk;
      }
    }
    __asm__ __volatile__("s_waitcnt lgkmcnt(0)" ::: "memory");
    #pragma unroll
    for (int rt = 0; rt < 4; ++rt)
      #pragma unroll
      for (int k2 = 0; k2 < 2; ++k2)
        aF[cc][rt][k2] = *reinterpret_cast<const bf16x8*>(
            sT + (wv * 64 + rt * 16 + l15) * LDT + k2 * 32 + q * 8);
    __asm__ __volatile__("s_waitcnt lgkmcnt(0)" ::: "memory");  // WAR guard
  }

  // ---- phase 2+3: d = relu(h1 @ W2 + b2) . W3 — ZERO LDS, ZERO barriers ----
  // B-frags stream straight from W2T (global): per instr 16 cache lines,
  // fully coalesced; 16 KB/chunk shared by all 8 resident waves via L1/L2.
  float dacc[4][4];
  #pragma unroll
  for (int rt = 0; rt < 4; ++rt)
    #pragma unroll
    for (int r = 0; r < 4; ++r) dacc[rt][r] = 0.f;

  #pragma unroll 2
  for (int ch = 0; ch < 8; ++ch) {
    float pb2v[2], pw3v[2];
    #pragma unroll
    for (int ct = 0; ct < 2; ++ct) {
      const int n = ch * 32 + ct * 16 + l15;
      pb2v[ct] = b2[c * HD + n];
      pw3v[ct] = W3[c * HD + n];
    }

    f32x4 acc[4][2];
    #pragma unroll
    for (int rt = 0; rt < 4; ++rt)
      #pragma unroll
      for (int ct = 0; ct < 2; ++ct)
        acc[rt][ct] = (f32x4){0.f, 0.f, 0.f, 0.f};

    #pragma unroll
    for (int ks = 0; ks < 8; ++ks) {
      const int koff = ks * 32 + q * 8;
      const int cc = ks >> 1, k2 = ks & 1;
      #pragma unroll
      for (int ct = 0; ct < 2; ++ct) {
        bf16x8 bW = *reinterpret_cast<const bf16x8*>(
            W2c + (ch * 32 + ct * 16 + l15) * HD + koff);
        #pragma unroll
        for (int rt = 0; rt < 4; ++rt)
          acc[rt][ct] = __builtin_amdgcn_mfma_f32_16x16x32_bf16(
              aF[cc][rt][k2], bW, acc[rt][ct], 0, 0, 0);
      }
    }

    // fused epilogue: relu(h2 + b2) dot W3 per row
    #pragma unroll
    for (int ct = 0; ct < 2; ++ct) {
      const float bias = pb2v[ct];
      const float w3v  = pw3v[ct];
      #pragma unroll
      for (int rt = 0; rt < 4; ++rt)
        #pragma unroll
        for (int r = 0; r < 4; ++r) {
          float v = acc[rt][ct][r] + bias;
          v = v > 0.f ? v : 0.f;
          dacc[rt][r] += v * w3v;
        }
    }
  }

  // ---- reduce over the 16 col-lanes, write out ----
  #pragma unroll
  for (int rt = 0; rt < 4; ++rt)
    #pragma unroll
    for (int r = 0; r < 4; ++r) {
      float v = dacc[rt][r];
      v += __shfl_xor(v, 1);
      v += __shfl_xor(v, 2);
      v += __shfl_xor(v, 4);
      v += __shfl_xor(v, 8);
      dacc[rt][r] = v;
    }

  if (l15 == 0) {
    const float bb3 = b3[c];
    const int rbase = row0 + wv * 64 + q * 4;
    #pragma unroll
    for (int rt = 0; rt < 4; ++rt)
      #pragma unroll
      for (int r = 0; r < 4; ++r)
        out[(rbase + rt * 16 + r) * C + c] = dacc[rt][r] + bb3;
  }
}

extern "C" void kernel_launch(void* const* d_in, const int* in_sizes, int n_in,
                              void* d_out, int out_size, void* d_ws, size_t ws_size,
                              hipStream_t stream)
{
  const float* st = (const float*)d_in[0];
  const float* W1 = (const float*)d_in[1];
  const float* b1 = (const float*)d_in[2];
  const float* W2 = (const float*)d_in[3];
  const float* b2 = (const float*)d_in[4];
  const float* W3 = (const float*)d_in[5];
  const float* b3 = (const float*)d_in[6];
  float* out = (float*)d_out;

  unsigned short* W1T = (unsigned short*)d_ws;         // 131072 bf16
  unsigned short* W2T = W1T + C * HD * S;              // 524288 bf16

  prep_weights<<<dim3(640), dim3(256), 0, stream>>>(W1, W2, W1T, W2T);
  moe_fused<<<dim3(2048), dim3(256), 0, stream>>>(st, W1T, W2T, b1, b2, W3, b3, out);
}

// Round 7
// 189.418 us; speedup vs baseline: 1.2731x; 1.2731x over previous
//
#include <hip/hip_runtime.h>
#include <hip/hip_bf16.h>

typedef __bf16 bf16x8 __attribute__((ext_vector_type(8)));
typedef float  f32x4  __attribute__((ext_vector_type(4)));

static constexpr int S  = 64;    // DIM_S
static constexpr int C  = 8;     // DIM_C (experts)
static constexpr int HD = 256;   // hidden width

__device__ __forceinline__ unsigned short f2bf(float f) {
  __hip_bfloat16 b = __float2bfloat16(f);
  unsigned short u;
  __builtin_memcpy(&u, &b, 2);
  return u;
}

// async global->LDS DMA, 16 B per lane; lds dest = wave-uniform base + lane*16
__device__ __forceinline__ void gl2lds16(const void* g, void* l) {
  __builtin_amdgcn_global_load_lds(
      (const __attribute__((address_space(1))) unsigned int*)g,
      (__attribute__((address_space(3))) unsigned int*)l, 16, 0, 0);
}

// LDS-tiled transposes, coalesced both sides.
// blocks 0..511:  W2 [C][256k][256n] -> W2T bf16 [C][256n][256k]
// blocks 512..639: W1 [C][64s][256h] -> W1T bf16 [C][256h][64s]
__global__ __launch_bounds__(256) void prep_weights(
    const float* __restrict__ W1, const float* __restrict__ W2,
    unsigned short* __restrict__ W1T, unsigned short* __restrict__ W2T)
{
  __shared__ float tile[32][33];
  const int tid = threadIdx.x, cl = tid & 31, r0 = tid >> 5;
  const int b = blockIdx.x;
  if (b < 512) {
    const int c = b >> 6, t = b & 63, kt = t >> 3, nt = t & 7;
    const float* src = W2 + c * 65536;
    #pragma unroll
    for (int i = 0; i < 4; ++i) {
      int r = r0 + 8 * i;
      tile[r][cl] = src[(kt * 32 + r) * 256 + nt * 32 + cl];
    }
    __syncthreads();
    unsigned short* dst = W2T + c * 65536;
    #pragma unroll
    for (int i = 0; i < 4; ++i) {
      int r = r0 + 8 * i;
      dst[(nt * 32 + r) * 256 + kt * 32 + cl] = f2bf(tile[cl][r]);
    }
  } else {
    const int bb = b - 512;
    const int c = bb >> 4, t = bb & 15, st2 = t >> 3, ht = t & 7;
    const float* src = W1 + c * 16384;
    #pragma unroll
    for (int i = 0; i < 4; ++i) {
      int r = r0 + 8 * i;
      tile[r][cl] = src[(st2 * 32 + r) * 256 + ht * 32 + cl];
    }
    __syncthreads();
    unsigned short* dst = W1T + c * 16384;
    #pragma unroll
    for (int i = 0; i < 4; ++i) {
      int r = r0 + 8 * i;
      dst[(ht * 32 + r) * 64 + st2 * 32 + cl] = f2bf(tile[cl][r]);
    }
  }
}

// One block: 256 batch rows x 1 expert. 4 waves, 64 rows/wave.
// Phase 1 TRANSPOSED (h1^T = W1^T @ st^T): packed b64 transpose, wave-private,
// barrier-free. Phase 2: W2T chunks via global_load_lds ping-pong (R5-proven).
// LDS: sT 36864 + sW2 32768 = 69632 B -> 2 blocks/CU.
__global__ __launch_bounds__(256, 2) void moe_fused(
    const float* __restrict__ st,
    const unsigned short* __restrict__ W1T,
    const unsigned short* __restrict__ W2T,
    const float* __restrict__ b1,
    const float* __restrict__ b2,
    const float* __restrict__ W3,
    const float* __restrict__ b3,
    float* __restrict__ out)
{
  constexpr int LDT = 72;   // sT pitch: 64 + 8 pad bf16 (144 B rows, 16B-aligned)

  __shared__ __align__(16) unsigned short sT[256 * LDT];     // 36864 B
  // W2 ping-pong: 2 chunks x 32 rows x 256 bf16, NO pad (DMA-contiguous).
  // Swizzle: phys granule p = j ^ (row&7)  (granule = 8 bf16 = 16 B)
  __shared__ __align__(16) unsigned short sW2[2 * 32 * 256]; // 32768 B

  const int tid  = threadIdx.x;
  const int lane = tid & 63;
  const int wv   = tid >> 6;          // wave -> batch rows [wv*64, wv*64+64)
  const int l15  = lane & 15;
  const int q    = lane >> 4;
  const int c    = blockIdx.x >> 8;
  const int row0 = (blockIdx.x & 255) * 256;

  const unsigned short* W1c = W1T + c * HD * S;
  const unsigned short* W2c = W2T + c * HD * HD;

  // ---- st B-fragments (batch as N): lane holds st[row][s=q*8+j], fp32->bf16 ----
  bf16x8 aA[4][2];   // [nt][ks]
  #pragma unroll
  for (int nt = 0; nt < 4; ++nt)
    #pragma unroll
    for (int ks = 0; ks < 2; ++ks) {
      const int row = row0 + wv * 64 + nt * 16 + l15;
      const float4* p = reinterpret_cast<const float4*>(st + (size_t)row * S + ks * 32 + q * 8);
      float4 x = p[0], y = p[1];
      union { bf16x8 v; unsigned short u[8]; } a;
      a.u[0] = f2bf(x.x); a.u[1] = f2bf(x.y); a.u[2] = f2bf(x.z); a.u[3] = f2bf(x.w);
      a.u[4] = f2bf(y.x); a.u[5] = f2bf(y.y); a.u[6] = f2bf(y.z); a.u[7] = f2bf(y.w);
      aA[nt][ks] = a.v;
    }

  float pb2v[8][2], pw3v[8][2], bb3;   // phase-2/3 scalars (loaded in quarter 3)

  // ---- phase 1: h1^T[hidden][batch], 4 quarters of 64 hidden ----
  bf16x8 aF[4][4][2];  // [cc][rt][k2]: phase-2 A-frags (m=batch l15, k=hidden)
  #pragma unroll
  for (int cc = 0; cc < 4; ++cc) {
    // quarter top: ALL global loads for this quarter (bias + 8x b128 W1)
    f32x4 bias[4];
    #pragma unroll
    for (int mt = 0; mt < 4; ++mt)
      bias[mt] = *reinterpret_cast<const f32x4*>(
          b1 + c * HD + cc * 64 + mt * 16 + q * 4);
    bf16x8 aW[2][4];
    #pragma unroll
    for (int ks = 0; ks < 2; ++ks)
      #pragma unroll
      for (int mt = 0; mt < 4; ++mt)
        aW[ks][mt] = *reinterpret_cast<const bf16x8*>(
            W1c + (cc * 64 + mt * 16 + l15) * S + ks * 32 + q * 8);

    if (cc == 3) {
      // phase-2/3 scalar preloads: must be OLDER than any DMA (vmcnt FIFO)
      #pragma unroll
      for (int ch = 0; ch < 8; ++ch)
        #pragma unroll
        for (int ct = 0; ct < 2; ++ct) {
          const int n = ch * 32 + ct * 16 + l15;
          pb2v[ch][ct] = b2[c * HD + n];
          pw3v[ch][ct] = W3[c * HD + n];
        }
      bb3 = b3[c];
      // DMA prologue: W2 chunks 0,1 — issued after the LAST phase-1 global
      // load, so no MFMA-feeding wait ever drains a DMA.
      #pragma unroll
      for (int pc = 0; pc < 2; ++pc) {
        unsigned short* buf = sW2 + pc * (32 * 256);
        #pragma unroll
        for (int i = 0; i < 4; ++i) {
          const int b2i = wv * 4 + i;            // 1KB unit (2 rows)
          const int r   = b2i * 2 + (lane >> 5); // local row 0..31
          const int j   = (lane & 31) ^ (r & 7); // logical granule
          gl2lds16(W2c + (pc * 32 + r) * 256 + j * 8, buf + b2i * 512);
        }
      }
    }

    f32x4 acc[4][4];   // [mt(hidden)][nt(batch)]
    #pragma unroll
    for (int mt = 0; mt < 4; ++mt)
      #pragma unroll
      for (int nt = 0; nt < 4; ++nt)
        acc[mt][nt] = (f32x4){0.f, 0.f, 0.f, 0.f};

    #pragma unroll
    for (int ks = 0; ks < 2; ++ks)
      #pragma unroll
      for (int mt = 0; mt < 4; ++mt)
        #pragma unroll
        for (int nt = 0; nt < 4; ++nt)
          acc[mt][nt] = __builtin_amdgcn_mfma_f32_16x16x32_bf16(
              aW[ks][mt], aA[nt][ks], acc[mt][nt], 0, 0, 0);

    // epilogue: +bias, relu, pack 4 consecutive hidden -> one b64 write.
    // sT rows [wv*64, wv*64+64) are wave-private: lgkmcnt drain, no barrier.
    #pragma unroll
    for (int mt = 0; mt < 4; ++mt) {
      #pragma unroll
      for (int nt = 0; nt < 4; ++nt) {
        ushort4 pk;
        float v0 = acc[mt][nt][0] + bias[mt][0]; v0 = v0 > 0.f ? v0 : 0.f;
        float v1 = acc[mt][nt][1] + bias[mt][1]; v1 = v1 > 0.f ? v1 : 0.f;
        float v2 = acc[mt][nt][2] + bias[mt][2]; v2 = v2 > 0.f ? v2 : 0.f;
        float v3 = acc[mt][nt][3] + bias[mt][3]; v3 = v3 > 0.f ? v3 : 0.f;
        pk.x = f2bf(v0); pk.y = f2bf(v1); pk.z = f2bf(v2); pk.w = f2bf(v3);
        *reinterpret_cast<ushort4*>(
            sT + (wv * 64 + nt * 16 + l15) * LDT + mt * 16 + q * 4) = pk;
      }
    }
    __asm__ __volatile__("s_waitcnt lgkmcnt(0)" ::: "memory");
    #pragma unroll
    for (int rt = 0; rt < 4; ++rt)
      #pragma unroll
      for (int k2 = 0; k2 < 2; ++k2)
        aF[cc][rt][k2] = *reinterpret_cast<const bf16x8*>(
            sT + (wv * 64 + rt * 16 + l15) * LDT + k2 * 32 + q * 8);
    __asm__ __volatile__("s_waitcnt lgkmcnt(0)" ::: "memory");  // WAR guard
  }

  __syncthreads();   // drains vmcnt(0): chunks 0,1 landed; all waves ready

  // ---- phase 2+3: d = relu(h1 @ W2 + b2) . W3, chunk ping-pong ----
  float dacc[4][4];
  #pragma unroll
  for (int rt = 0; rt < 4; ++rt)
    #pragma unroll
    for (int r = 0; r < 4; ++r) dacc[rt][r] = 0.f;

  #pragma unroll
  for (int ch = 0; ch < 8; ++ch) {
    const unsigned short* buf = sW2 + (ch & 1) * (32 * 256);

    f32x4 acc[4][2];
    #pragma unroll
    for (int rt = 0; rt < 4; ++rt)
      #pragma unroll
      for (int ct = 0; ct < 2; ++ct)
        acc[rt][ct] = (f32x4){0.f, 0.f, 0.f, 0.f};

    #pragma unroll
    for (int ks = 0; ks < 8; ++ks) {
      const int jj = ks * 4 + q;            // logical granule of this k-slice
      const int cc = ks >> 1, k2 = ks & 1;
      #pragma unroll
      for (int ct = 0; ct < 2; ++ct) {
        const int nl = ct * 16 + l15;       // local row (= h2 col within chunk)
        bf16x8 b = *reinterpret_cast<const bf16x8*>(
            buf + nl * 256 + ((jj ^ (l15 & 7)) << 3));
        #pragma unroll
        for (int rt = 0; rt < 4; ++rt)
          acc[rt][ct] = __builtin_amdgcn_mfma_f32_16x16x32_bf16(
              aF[cc][rt][k2], b, acc[rt][ct], 0, 0, 0);
      }
    }

    // fused epilogue: relu(h2 + b2) dot W3 per row (all operands in regs)
    #pragma unroll
    for (int ct = 0; ct < 2; ++ct) {
      const float bias = pb2v[ch][ct];
      const float w3v  = pw3v[ch][ct];
      #pragma unroll
      for (int rt = 0; rt < 4; ++rt)
        #pragma unroll
        for (int r = 0; r < 4; ++r) {
          float v = acc[rt][ct][r] + bias;
          v = v > 0.f ? v : 0.f;
          dacc[rt][r] += v * w3v;
        }
    }

    __syncthreads();   // readers of buf[ch&1] done; drains chunk ch+1's DMA
    if (ch < 6) {      // refill freed buffer with chunk ch+2 (1 chunk in flight)
      unsigned short* nbuf = sW2 + (ch & 1) * (32 * 256);
      #pragma unroll
      for (int i = 0; i < 4; ++i) {
        const int b2i = wv * 4 + i;
        const int r   = b2i * 2 + (lane >> 5);
        const int j   = (lane & 31) ^ (r & 7);
        gl2lds16(W2c + ((ch + 2) * 32 + r) * 256 + j * 8, nbuf + b2i * 512);
      }
    }
  }

  // ---- reduce over the 16 col-lanes, write out ----
  #pragma unroll
  for (int rt = 0; rt < 4; ++rt)
    #pragma unroll
    for (int r = 0; r < 4; ++r) {
      float v = dacc[rt][r];
      v += __shfl_xor(v, 1);
      v += __shfl_xor(v, 2);
      v += __shfl_xor(v, 4);
      v += __shfl_xor(v, 8);
      dacc[rt][r] = v;
    }

  if (l15 == 0) {
    const int rbase = row0 + wv * 64 + q * 4;
    #pragma unroll
    for (int rt = 0; rt < 4; ++rt)
      #pragma unroll
      for (int r = 0; r < 4; ++r)
        out[(rbase + rt * 16 + r) * C + c] = dacc[rt][r] + bb3;
  }
}

extern "C" void kernel_launch(void* const* d_in, const int* in_sizes, int n_in,
                              void* d_out, int out_size, void* d_ws, size_t ws_size,
                              hipStream_t stream)
{
  const float* st = (const float*)d_in[0];
  const float* W1 = (const float*)d_in[1];
  const float* b1 = (const float*)d_in[2];
  const float* W2 = (const float*)d_in[3];
  const float* b2 = (const float*)d_in[4];
  const float* W3 = (const float*)d_in[5];
  const float* b3 = (const float*)d_in[6];
  float* out = (float*)d_out;

  unsigned short* W1T = (unsigned short*)d_ws;         // 131072 bf16
  unsigned short* W2T = W1T + C * HD * S;              // 524288 bf16

  prep_weights<<<dim3(640), dim3(256), 0, stream>>>(W1, W2, W1T, W2T);
  moe_fused<<<dim3(2048), dim3(256), 0, stream>>>(st, W1T, W2T, b1, b2, W3, b3, out);
}

// Round 8
// 168.132 us; speedup vs baseline: 1.4343x; 1.1266x over previous
//
#include <hip/hip_runtime.h>
#include <hip/hip_bf16.h>

typedef __bf16 bf16x8 __attribute__((ext_vector_type(8)));
typedef float  f32x4  __attribute__((ext_vector_type(4)));

static constexpr int S  = 64;    // DIM_S
static constexpr int C  = 8;     // DIM_C (experts)
static constexpr int HD = 256;   // hidden width

__device__ __forceinline__ unsigned short f2bf(float f) {
  __hip_bfloat16 b = __float2bfloat16(f);
  unsigned short u;
  __builtin_memcpy(&u, &b, 2);
  return u;
}

// async global->LDS DMA, 16 B per lane; lds dest = wave-uniform base + lane*16
__device__ __forceinline__ void gl2lds16(const void* g, void* l) {
  __builtin_amdgcn_global_load_lds(
      (const __attribute__((address_space(1))) unsigned int*)g,
      (__attribute__((address_space(3))) unsigned int*)l, 16, 0, 0);
}

// LDS-tiled transposes, coalesced both sides.
// blocks 0..511:  W2 [C][256k][256n] -> W2T bf16 [C][256n][256k]
// blocks 512..639: W1 [C][64s][256h] -> W1T bf16 [C][256h][64s]
__global__ __launch_bounds__(256) void prep_weights(
    const float* __restrict__ W1, const float* __restrict__ W2,
    unsigned short* __restrict__ W1T, unsigned short* __restrict__ W2T)
{
  __shared__ float tile[32][33];
  const int tid = threadIdx.x, cl = tid & 31, r0 = tid >> 5;
  const int b = blockIdx.x;
  if (b < 512) {
    const int c = b >> 6, t = b & 63, kt = t >> 3, nt = t & 7;
    const float* src = W2 + c * 65536;
    #pragma unroll
    for (int i = 0; i < 4; ++i) {
      int r = r0 + 8 * i;
      tile[r][cl] = src[(kt * 32 + r) * 256 + nt * 32 + cl];
    }
    __syncthreads();
    unsigned short* dst = W2T + c * 65536;
    #pragma unroll
    for (int i = 0; i < 4; ++i) {
      int r = r0 + 8 * i;
      dst[(nt * 32 + r) * 256 + kt * 32 + cl] = f2bf(tile[cl][r]);
    }
  } else {
    const int bb = b - 512;
    const int c = bb >> 4, t = bb & 15, st2 = t >> 3, ht = t & 7;
    const float* src = W1 + c * 16384;
    #pragma unroll
    for (int i = 0; i < 4; ++i) {
      int r = r0 + 8 * i;
      tile[r][cl] = src[(st2 * 32 + r) * 256 + ht * 32 + cl];
    }
    __syncthreads();
    unsigned short* dst = W1T + c * 16384;
    #pragma unroll
    for (int i = 0; i < 4; ++i) {
      int r = r0 + 8 * i;
      dst[(ht * 32 + r) * 64 + st2 * 32 + cl] = f2bf(tile[cl][r]);
    }
  }
}

// One block: 256 batch rows x 1 expert. 4 waves, 64 rows/wave.
// Register diet: st tile lives in LDS (sU) during phase 1, freeing 64 VGPRs;
// sU is reused as the phase-2 W2 DMA ping-pong after barrier #1.
// LDS: sT 36864 + sU 32768 = 69632 B -> 2 blocks/CU (register-capped anyway).
__global__ __launch_bounds__(256, 2) void moe_fused(
    const float* __restrict__ st,
    const unsigned short* __restrict__ W1T,
    const unsigned short* __restrict__ W2T,
    const float* __restrict__ b1,
    const float* __restrict__ b2,
    const float* __restrict__ W3,
    const float* __restrict__ b3,
    float* __restrict__ out)
{
  constexpr int LDT = 72;   // sT pitch: 64 + 8 pad bf16 (144 B rows, 16B-aligned)

  __shared__ __align__(16) unsigned short sT[256 * LDT];   // 36864 B transpose buf
  // sU: phase 1 = st tile bf16 [256 rows][64], granule-swizzled (g^(r&7));
  //     phase 2 = W2 ping-pong 2 x (32 rows x 256 bf16), same swizzle. 32768 B.
  __shared__ __align__(16) unsigned short sU[2 * 32 * 256];

  const int tid  = threadIdx.x;
  const int lane = tid & 63;
  const int wv   = tid >> 6;          // wave -> batch rows [wv*64, wv*64+64)
  const int l15  = lane & 15;
  const int q    = lane >> 4;
  const int c    = blockIdx.x >> 8;
  const int row0 = (blockIdx.x & 255) * 256;

  const unsigned short* W1c = W1T + c * HD * S;
  const unsigned short* W2c = W2T + c * HD * HD;

  // ---- stage st (fp32 -> bf16) into sU; wave-private rows, swizzled ----
  {
    #pragma unroll
    for (int it = 0; it < 8; ++it) {
      const int r = wv * 64 + it * 8 + (lane >> 3);   // block-local batch row
      const int g = lane & 7;                          // logical granule (8 bf16)
      const float4* p = reinterpret_cast<const float4*>(
          st + (size_t)(row0 + r) * S + g * 8);
      float4 x = p[0], y = p[1];
      union { uint4 u4; unsigned short us[8]; } pk;
      pk.us[0] = f2bf(x.x); pk.us[1] = f2bf(x.y); pk.us[2] = f2bf(x.z); pk.us[3] = f2bf(x.w);
      pk.us[4] = f2bf(y.x); pk.us[5] = f2bf(y.y); pk.us[6] = f2bf(y.z); pk.us[7] = f2bf(y.w);
      *reinterpret_cast<uint4*>(sU + r * 64 + ((g ^ (r & 7)) << 3)) = pk.u4;
    }
  }
  __asm__ __volatile__("s_waitcnt lgkmcnt(0)" ::: "memory");

  // ---- phase 1: h1^T[hidden][batch] = W1^T @ st^T, 4 quarters of 64 hidden ----
  bf16x8 aF[4][4][2];  // [cc][rt][k2]: phase-2 A-frags (m=batch l15, k=hidden)
  #pragma unroll
  for (int cc = 0; cc < 4; ++cc) {
    f32x4 bias[4];
    #pragma unroll
    for (int mt = 0; mt < 4; ++mt)
      bias[mt] = *reinterpret_cast<const f32x4*>(
          b1 + c * HD + cc * 64 + mt * 16 + q * 4);

    f32x4 acc[4][4];   // [mt(hidden)][nt(batch)]
    #pragma unroll
    for (int mt = 0; mt < 4; ++mt)
      #pragma unroll
      for (int nt = 0; nt < 4; ++nt)
        acc[mt][nt] = (f32x4){0.f, 0.f, 0.f, 0.f};

    #pragma unroll
    for (int ks = 0; ks < 2; ++ks) {
      // A-frags: W1T rows (hidden as M), global, L1/L2-hot under c-major grid
      bf16x8 aW[4];
      #pragma unroll
      for (int mt = 0; mt < 4; ++mt)
        aW[mt] = *reinterpret_cast<const bf16x8*>(
            W1c + (cc * 64 + mt * 16 + l15) * S + ks * 32 + q * 8);
      // B-frags: st rows (batch as N) from swizzled sU
      bf16x8 bB[4];
      #pragma unroll
      for (int nt = 0; nt < 4; ++nt) {
        const int r = wv * 64 + nt * 16 + l15;
        const int g = ks * 4 + q;
        bB[nt] = *reinterpret_cast<const bf16x8*>(
            sU + r * 64 + ((g ^ (r & 7)) << 3));
      }
      #pragma unroll
      for (int mt = 0; mt < 4; ++mt)
        #pragma unroll
        for (int nt = 0; nt < 4; ++nt)
          acc[mt][nt] = __builtin_amdgcn_mfma_f32_16x16x32_bf16(
              aW[mt], bB[nt], acc[mt][nt], 0, 0, 0);
    }

    // epilogue: +bias, relu, pack 4 consecutive hidden -> one b64 write.
    // sT rows [wv*64, wv*64+64) are wave-private: lgkmcnt drain, no barrier.
    #pragma unroll
    for (int mt = 0; mt < 4; ++mt) {
      #pragma unroll
      for (int nt = 0; nt < 4; ++nt) {
        ushort4 pk;
        float v0 = acc[mt][nt][0] + bias[mt][0]; v0 = v0 > 0.f ? v0 : 0.f;
        float v1 = acc[mt][nt][1] + bias[mt][1]; v1 = v1 > 0.f ? v1 : 0.f;
        float v2 = acc[mt][nt][2] + bias[mt][2]; v2 = v2 > 0.f ? v2 : 0.f;
        float v3 = acc[mt][nt][3] + bias[mt][3]; v3 = v3 > 0.f ? v3 : 0.f;
        pk.x = f2bf(v0); pk.y = f2bf(v1); pk.z = f2bf(v2); pk.w = f2bf(v3);
        *reinterpret_cast<ushort4*>(
            sT + (wv * 64 + nt * 16 + l15) * LDT + mt * 16 + q * 4) = pk;
      }
    }
    __asm__ __volatile__("s_waitcnt lgkmcnt(0)" ::: "memory");
    #pragma unroll
    for (int rt = 0; rt < 4; ++rt)
      #pragma unroll
      for (int k2 = 0; k2 < 2; ++k2)
        aF[cc][rt][k2] = *reinterpret_cast<const bf16x8*>(
            sT + (wv * 64 + rt * 16 + l15) * LDT + k2 * 32 + q * 8);
    __asm__ __volatile__("s_waitcnt lgkmcnt(0)" ::: "memory");  // WAR guard
  }

  // ---- phase-2/3 scalars: loaded BEFORE any DMA is issued (vmcnt FIFO) ----
  float pb2v[8][2], pw3v[8][2];
  #pragma unroll
  for (int ch = 0; ch < 8; ++ch)
    #pragma unroll
    for (int ct = 0; ct < 2; ++ct) {
      const int n = ch * 32 + ct * 16 + l15;
      pb2v[ch][ct] = b2[c * HD + n];
      pw3v[ch][ct] = W3[c * HD + n];
    }
  const float bb3 = b3[c];

  __syncthreads();   // barrier #1: ALL waves done reading sU-as-st (union safety)

  // ---- DMA prologue: W2 chunks 0,1 into sU (now free) ----
  #pragma unroll
  for (int pc = 0; pc < 2; ++pc) {
    unsigned short* buf = sU + pc * (32 * 256);
    #pragma unroll
    for (int i = 0; i < 4; ++i) {
      const int b2i = wv * 4 + i;            // 1KB unit (2 rows)
      const int r   = b2i * 2 + (lane >> 5); // local row 0..31
      const int j   = (lane & 31) ^ (r & 7); // logical granule
      gl2lds16(W2c + (pc * 32 + r) * 256 + j * 8, buf + b2i * 512);
    }
  }
  __syncthreads();   // barrier #2: drains vmcnt(0) -> chunks 0,1 landed

  // ---- phase 2+3: d = relu(h1 @ W2 + b2) . W3, chunk ping-pong ----
  float dacc[4][4];
  #pragma unroll
  for (int rt = 0; rt < 4; ++rt)
    #pragma unroll
    for (int r = 0; r < 4; ++r) dacc[rt][r] = 0.f;

  #pragma unroll
  for (int ch = 0; ch < 8; ++ch) {
    const unsigned short* buf = sU + (ch & 1) * (32 * 256);

    f32x4 acc[4][2];
    #pragma unroll
    for (int rt = 0; rt < 4; ++rt)
      #pragma unroll
      for (int ct = 0; ct < 2; ++ct)
        acc[rt][ct] = (f32x4){0.f, 0.f, 0.f, 0.f};

    #pragma unroll
    for (int ks = 0; ks < 8; ++ks) {
      const int jj = ks * 4 + q;            // logical granule of this k-slice
      const int cc = ks >> 1, k2 = ks & 1;
      #pragma unroll
      for (int ct = 0; ct < 2; ++ct) {
        const int nl = ct * 16 + l15;       // local row (= h2 col within chunk)
        bf16x8 b = *reinterpret_cast<const bf16x8*>(
            buf + nl * 256 + ((jj ^ (l15 & 7)) << 3));
        #pragma unroll
        for (int rt = 0; rt < 4; ++rt)
          acc[rt][ct] = __builtin_amdgcn_mfma_f32_16x16x32_bf16(
              aF[cc][rt][k2], b, acc[rt][ct], 0, 0, 0);
      }
    }

    // fused epilogue: relu(h2 + b2) dot W3 per row (all operands in regs)
    #pragma unroll
    for (int ct = 0; ct < 2; ++ct) {
      const float bias = pb2v[ch][ct];
      const float w3v  = pw3v[ch][ct];
      #pragma unroll
      for (int rt = 0; rt < 4; ++rt)
        #pragma unroll
        for (int r = 0; r < 4; ++r) {
          float v = acc[rt][ct][r] + bias;
          v = v > 0.f ? v : 0.f;
          dacc[rt][r] += v * w3v;
        }
    }

    __syncthreads();   // readers of buf[ch&1] done; drains chunk ch+1's DMA
    if (ch < 6) {      // refill freed buffer with chunk ch+2 (1 chunk in flight)
      unsigned short* nbuf = sU + (ch & 1) * (32 * 256);
      #pragma unroll
      for (int i = 0; i < 4; ++i) {
        const int b2i = wv * 4 + i;
        const int r   = b2i * 2 + (lane >> 5);
        const int j   = (lane & 31) ^ (r & 7);
        gl2lds16(W2c + ((ch + 2) * 32 + r) * 256 + j * 8, nbuf + b2i * 512);
      }
    }
  }

  // ---- reduce over the 16 col-lanes, write out ----
  #pragma unroll
  for (int rt = 0; rt < 4; ++rt)
    #pragma unroll
    for (int r = 0; r < 4; ++r) {
      float v = dacc[rt][r];
      v += __shfl_xor(v, 1);
      v += __shfl_xor(v, 2);
      v += __shfl_xor(v, 4);
      v += __shfl_xor(v, 8);
      dacc[rt][r] = v;
    }

  if (l15 == 0) {
    const int rbase = row0 + wv * 64 + q * 4;
    #pragma unroll
    for (int rt = 0; rt < 4; ++rt)
      #pragma unroll
      for (int r = 0; r < 4; ++r)
        out[(rbase + rt * 16 + r) * C + c] = dacc[rt][r] + bb3;
  }
}

extern "C" void kernel_launch(void* const* d_in, const int* in_sizes, int n_in,
                              void* d_out, int out_size, void* d_ws, size_t ws_size,
                              hipStream_t stream)
{
  const float* st = (const float*)d_in[0];
  const float* W1 = (const float*)d_in[1];
  const float* b1 = (const float*)d_in[2];
  const float* W2 = (const float*)d_in[3];
  const float* b2 = (const float*)d_in[4];
  const float* W3 = (const float*)d_in[5];
  const float* b3 = (const float*)d_in[6];
  float* out = (float*)d_out;

  unsigned short* W1T = (unsigned short*)d_ws;         // 131072 bf16
  unsigned short* W2T = W1T + C * HD * S;              // 524288 bf16

  prep_weights<<<dim3(640), dim3(256), 0, stream>>>(W1, W2, W1T, W2T);
  moe_fused<<<dim3(2048), dim3(256), 0, stream>>>(st, W1T, W2T, b1, b2, W3, b3, out);
}